// Round 7
// baseline (353.624 us; speedup 1.0000x reference)
//
#include <hip/hip_runtime.h>

typedef unsigned int u32;
typedef unsigned short u16;
typedef unsigned long long u64;
typedef __attribute__((ext_vector_type(8))) short bf16x8;
typedef __attribute__((ext_vector_type(4))) float f32x4;
typedef __attribute__((ext_vector_type(4))) u32 u32x4;

// ---------------- workspace layout (floats) ----------------
#define REL_OFF   0
#define PTS4_OFF  1572864   // pts4 during prep/knn (131072 fl). Fallback path
                            // reuses it (dead after knn) for w2h/w2l/gsum/gsq.
#define ACC_OFF   1703936   // mom[16]  (zeroed by prep each launch)
#define EXT_OFF   1705360   // big-ws path: w2h(2048)|w2l(2048)|gsum32(2048)|gsq32(2048)
#define EXT_END   1713552   // floats; big path needs ws_size >= EXT_END*4 bytes

__device__ __forceinline__ u32 bfh(float v){           // RNE bf16 hi bits
  u32 x = __float_as_uint(v);
  return (x + 0x7FFFu + ((x >> 16) & 1u)) >> 16;
}
__device__ __forceinline__ void split2(float v, u16* hh, u16* hl){
  u32 h = bfh(v);
  float hif = __uint_as_float(h << 16);
  u32 l = bfh(v - hif);
  *hh = (u16)h; *hl = (u16)l;
}
// packed RNE bf16 convert: dst.lo = bf16(a), dst.hi = bf16(b).
__device__ __forceinline__ u32 cvt_pk_bf16(float a, float b){
  u32 r;
  asm("v_cvt_pk_bf16_f32 %0, %1, %2" : "=v"(r) : "v"(a), "v"(b));
  return r;
}
__device__ __forceinline__ bf16x8 as_bf16x8(u32x4 v){
  union { u32x4 u; bf16x8 b; } c; c.u = v; return c.b;
}

// ---- DPP rotate-reductions over the 16-lane DPP row (R18, proven) ----
template<int N>
__device__ __forceinline__ float dpp_ror_f(float x){
  int r = __builtin_amdgcn_update_dpp(__float_as_int(x), __float_as_int(x),
                                      0x120 + N, 0xf, 0xf, false);
  return __int_as_float(r);
}
__device__ __forceinline__ float row_sum16(float x){
  x += dpp_ror_f<1>(x);
  x += dpp_ror_f<2>(x);
  x += dpp_ror_f<4>(x);
  x += dpp_ror_f<8>(x);
  return x;
}
__device__ __forceinline__ float row_max16(float x){
  x = fmaxf(x, dpp_ror_f<1>(x));
  x = fmaxf(x, dpp_ror_f<2>(x));
  x = fmaxf(x, dpp_ror_f<4>(x));
  x = fmaxf(x, dpp_ror_f<8>(x));
  return x;
}

// prep absorbs W2 bf16-split + gsum/gsq zeroing (big-ws path, R17).
__global__ __launch_bounds__(256) void prep_kernel(const float* __restrict__ xyz,
                                                   float4* __restrict__ pts4,
                                                   float* __restrict__ mom,
                                                   const float* __restrict__ w2,
                                                   u16* __restrict__ w2h,
                                                   u16* __restrict__ w2l,
                                                   float* __restrict__ gsum32,
                                                   float* __restrict__ gsq32,
                                                   int do_w2){
#pragma clang fp contract(off)
  int g = blockIdx.x*256 + threadIdx.x;
  if (g < 16) mom[g] = 0.0f;
  if (do_w2){
    if (g < 4096) split2(w2[g], &w2h[g], &w2l[g]);
    if (g < 2048) gsum32[g] = 0.0f;
    else if (g < 4096) gsq32[g-2048] = 0.0f;
  }
  int b = g >> 12, n = g & 4095;
  const float* xb = xyz + (size_t)b*12288;
  float x = xb[n], y = xb[4096+n], z = xb[8192+n];
  float sq = (x*x + y*y) + z*z;
  pts4[g] = make_float4(x,y,z,sq);
}

// Fallback (small ws): W2 split + zeroing into dead pts4, after knn.
__global__ void w2prep_kernel(const float* __restrict__ w2,
                              u16* __restrict__ w2h, u16* __restrict__ w2l,
                              float* __restrict__ gsum32, float* __restrict__ gsq32){
  int i = blockIdx.x*256 + threadIdx.x;   // 4096
  split2(w2[i], &w2h[i], &w2l[i]);
  if (i < 2048) gsum32[i] = 0.0f; else gsq32[i-2048] = 0.0f;
}

// Parallel (depth-2) sorted-insert (R15).
template<int N>
__device__ __forceinline__ void chain_insert_n(double* s, double key){
  #pragma unroll
  for (int t = N-1; t >= 1; --t)
    s[t] = fmax(s[t], fmin(s[t-1], key));
  s[0] = fmax(s[0], key);
}

// KNN: burst-draining ring (R13) + parallel chain (R15). UNCHANGED.
__global__ __launch_bounds__(256) void knn_kernel(const float4* __restrict__ pts4,
                                                  float* __restrict__ rel,
                                                  float* __restrict__ mom){
#pragma clang fp contract(off)
  __shared__ double ring[4352];
  __shared__ float bmom[16];
  __shared__ u32 gate[32];
  u32* lA = (u32*)ring;
  u16* lB = (u16*)((char*)ring + 18048);
  const int tid  = threadIdx.x;
  const int lane = tid & 63;
  const int wave = tid >> 6;
  const int q    = lane & 31;
  const int h    = lane >> 5;
  const int sp   = wave*2 + h;
  const int blk  = blockIdx.x;
  const int b    = blk >> 7;
  const int q0   = (blk & 127) << 5;
  const float4* __restrict__ P = pts4 + ((size_t)b << 12);
  const float4* __restrict__ C = P + (sp << 9);
  const float4 me = P[q0 + q];
  if (tid < 16) bmom[tid] = 0.0f;
  if (tid < 32) gate[tid] = 0u;
  __syncthreads();

  double s[17];
  #pragma unroll
  for (int i=0;i<17;i++) s[i] = 0.0;
  const int base = tid*17;
  const int jg0 = sp << 9;
  u32 wr = 0, rd = 0;
  double pD_ = 0.0;
  const double kinv = 1.52587890625e-05;

  #define KEY48(u, J) ({                                              \
    float dot_ = (me.x*c[(u)].x + me.y*c[(u)].y) + me.z*c[(u)].z;     \
    float d_   = (me.w + c[(u)].w) - 2.0f*dot_;                       \
    u32 ub_ = __float_as_uint(d_);                                    \
    ub_ ^= ((u32)(((int)ub_) >> 31) | 0x80000000u);                   \
    (double)ub_ * 65536.0 + (double)(4095 - (J)); })

  { // warm-up candidates 0..7, triangular depths 1..8
    float4 c[8];
    #pragma unroll
    for (int u=0;u<8;u++) c[u] = C[u];
    chain_insert_n<1>(s, KEY48(0, jg0+0));
    chain_insert_n<2>(s, KEY48(1, jg0+1));
    chain_insert_n<3>(s, KEY48(2, jg0+2));
    chain_insert_n<4>(s, KEY48(3, jg0+3));
    chain_insert_n<5>(s, KEY48(4, jg0+4));
    chain_insert_n<6>(s, KEY48(5, jg0+5));
    chain_insert_n<7>(s, KEY48(6, jg0+6));
    chain_insert_n<8>(s, KEY48(7, jg0+7));
  }
  { // candidates 8..15, depths 9..16
    float4 c[8];
    #pragma unroll
    for (int u=0;u<8;u++) c[u] = C[8+u];
    chain_insert_n< 9>(s, KEY48(0, jg0+ 8));
    chain_insert_n<10>(s, KEY48(1, jg0+ 9));
    chain_insert_n<11>(s, KEY48(2, jg0+10));
    chain_insert_n<12>(s, KEY48(3, jg0+11));
    chain_insert_n<13>(s, KEY48(4, jg0+12));
    chain_insert_n<14>(s, KEY48(5, jg0+13));
    chain_insert_n<15>(s, KEY48(6, jg0+14));
    chain_insert_n<16>(s, KEY48(7, jg0+15));
  }
  { // candidates 16..23, full depth
    float4 c[8];
    #pragma unroll
    for (int u=0;u<8;u++) c[u] = C[16+u];
    #pragma unroll
    for (int u=0;u<8;u++) chain_insert_n<17>(s, KEY48(u, jg0+16+u));
  }

  u32 lastpub = (u32)(s[16] * kinv);
  atomicMax(&gate[q], lastpub);
  u32 ob = lastpub;

  #define INSERT_STEP() {                                        \
    bool act = rd != wr;                                         \
    double key = act ? pD_ : 0.0;                                \
    rd += act;                                                   \
    pD_ = ring[base + (int)(rd & 15u)];                          \
    if (__any(key > s[16])) chain_insert_n<17>(s, key);          \
  }

  for (int g8 = 24; g8 < 512; g8 += 8){
    if (__any((int)(wr - rd) >= 9)){
      do { INSERT_STEP(); } while (__any(rd != wr));
      ob = (u32)(s[16] * kinv);
      if (ob > lastpub){ atomicMax(&gate[q], ob); lastpub = ob; }
    }
    float4 c[8];
    #pragma unroll
    for (int u=0;u<8;u++) c[u] = C[g8 + u];
    const u32 mb = max(gate[q], ob);
    const u32 ib = (mb >> 31) ? (mb ^ 0x80000000u) : ~mb;
    const float gmin = __uint_as_float(ib);
    const u32 wr0 = wr;
    #pragma unroll
    for (int u=0;u<8;u++){
      const int j = jg0 + g8 + u;
      float dot = (me.x*c[u].x + me.y*c[u].y) + me.z*c[u].z;
      float d   = (me.w + c[u].w) - 2.0f*dot;
      if (d >= gmin){
        u32 ub = __float_as_uint(d);
        ub ^= ((u32)(((int)ub) >> 31) | 0x80000000u);
        ring[base + (int)(wr & 15u)] = (double)ub * 65536.0 + (double)(4095 - j);
        wr++;
      }
    }
    if (wr != wr0) pD_ = ring[base + (int)(rd & 15u)];
  }
  while (__any(rd != wr)) INSERT_STEP();
  #undef INSERT_STEP
  #undef KEY48

  __syncthreads();
  #pragma unroll
  for (int i=0;i<17;i++){
    const int o = (sp*17 + i)*33 + q;
    u32 hi = (u32)(s[i] * kinv);
    u32 lo = (u32)(s[i] - (double)hi * 65536.0);
    lA[o] = hi;
    lB[o] = (u16)lo;
  }
  __syncthreads();

  {
    const int mq  = tid >> 3;
    const int sub = tid & 7;
    const float4 qp = P[q0 + mq];
    float* __restrict__ ro = rel + (size_t)((b << 12) + q0 + mq) * 48;
    float sm0=0,sm1=0,sm2=0,sm3=0,sm4=0,sm5=0,sm6=0,sm7=0,sm8=0;
    int p = 0;
    for (int r=0;r<17;r++){
      const int idx = (sub*17 + p)*33 + mq;
      u64 mine = ((u64)lA[idx] << 16) | lB[idx];
      u64 kmax = mine;
      #pragma unroll
      for (int off=1; off<8; off<<=1){
        u64 o2 = __shfl_xor(kmax, off);
        kmax = (o2 > kmax) ? o2 : kmax;
      }
      p += (mine == kmax);
      if (r > 0 && sub == 0){
        const int j = 4095 - (int)(u32)(kmax & 0xFFFFull);
        const float4 nb = P[j];
        const float rx = nb.x - qp.x;
        const float ry = nb.y - qp.y;
        const float rz = nb.z - qp.z;
        ro[(r-1)*3+0] = rx; ro[(r-1)*3+1] = ry; ro[(r-1)*3+2] = rz;
        sm0 += rx; sm1 += ry; sm2 += rz;
        sm3 += rx*rx; sm4 += rx*ry; sm5 += rx*rz;
        sm6 += ry*ry; sm7 += ry*rz; sm8 += rz*rz;
      }
    }
    #pragma unroll
    for (int off=8; off<64; off<<=1){
      sm0 += __shfl_xor(sm0, off); sm1 += __shfl_xor(sm1, off); sm2 += __shfl_xor(sm2, off);
      sm3 += __shfl_xor(sm3, off); sm4 += __shfl_xor(sm4, off); sm5 += __shfl_xor(sm5, off);
      sm6 += __shfl_xor(sm6, off); sm7 += __shfl_xor(sm7, off); sm8 += __shfl_xor(sm8, off);
    }
    if (lane == 0){
      atomicAdd(&bmom[0], sm0); atomicAdd(&bmom[1], sm1); atomicAdd(&bmom[2], sm2);
      atomicAdd(&bmom[3], sm3); atomicAdd(&bmom[4], sm4); atomicAdd(&bmom[5], sm5);
      atomicAdd(&bmom[6], sm6); atomicAdd(&bmom[7], sm7); atomicAdd(&bmom[8], sm8);
    }
  }
  __syncthreads();
  if (tid < 9) atomicAdd(&mom[tid], bmom[tid]);
}

// BN1 analytic consts into LDS; __noinline__ => shared codegen in both passes.
__device__ __noinline__ void stats1_to_lds(int o, const float* __restrict__ mom,
    const float* __restrict__ w1, const float* __restrict__ b1,
    const float* __restrict__ gamma, const float* __restrict__ beta,
    float* a1){
  const float Minv = 1.0f / 524288.0f;
  float m0 = mom[0]*Minv, m1 = mom[1]*Minv, m2 = mom[2]*Minv;
  float cxx = mom[3]*Minv - m0*m0;
  float cxy = mom[4]*Minv - m0*m1;
  float cxz = mom[5]*Minv - m0*m2;
  float cyy = mom[6]*Minv - m1*m1;
  float cyz = mom[7]*Minv - m1*m2;
  float czz = mom[8]*Minv - m2*m2;
  float wx = w1[o*3+0], wy = w1[o*3+1], wz = w1[o*3+2];
  float mu  = wx*m0 + wy*m1 + wz*m2 + b1[o];
  float var = wx*wx*cxx + wy*wy*cyy + wz*wz*czz
            + 2.0f*(wx*wy*cxy + wx*wz*cxz + wy*wz*cyz);
  float istd = rsqrtf(var + 1e-5f);
  float sc = gamma[o]*istd;
  float t1 = beta[o] - mu*sc;
  a1[o*4+0] = wx*sc;
  a1[o*4+1] = wy*sc;
  a1[o*4+2] = wz*sc;
  a1[o*4+3] = fmaf(sc, b1[o], t1);
}

// ---- R19: H1 B-fragments born IN-REGISTER (wave owns 2 element-tiles x all
// 64 ch). Thread (wave,quad,col) computes H1 for its 2 elements, channels
// quad*8..+8 and +32..+8 -- exactly the MFMA B-fragment layout. Same per-value
// RNE rounding as the old LDS path => bit-identical H1. ----
__device__ __forceinline__ void stage2_reg(
    const float* a1s, int quad,
    float rx0,float ry0,float rz0, float rx1,float ry1,float rz1,
    bf16x8 bh0[2], bf16x8 bl0[2], bf16x8 bh1[2], bf16x8 bl1[2]){
  const float4* A1 = (const float4*)a1s;
  #pragma unroll
  for (int hf=0; hf<2; hf++){
    const int c0 = quad*8 + hf*32;
    u32x4 H0,L0,H1,L1;
    #pragma unroll
    for (int p=0;p<4;p++){
      float4 aA = A1[c0+2*p];
      float4 aB = A1[c0+2*p+1];
      float gA0 = fmaxf(fmaf(aA.x,rx0,fmaf(aA.y,ry0,fmaf(aA.z,rz0,aA.w))),0.f);
      float gB0 = fmaxf(fmaf(aB.x,rx0,fmaf(aB.y,ry0,fmaf(aB.z,rz0,aB.w))),0.f);
      float gA1 = fmaxf(fmaf(aA.x,rx1,fmaf(aA.y,ry1,fmaf(aA.z,rz1,aA.w))),0.f);
      float gB1 = fmaxf(fmaf(aB.x,rx1,fmaf(aB.y,ry1,fmaf(aB.z,rz1,aB.w))),0.f);
      u32 h0 = cvt_pk_bf16(gA0,gB0);
      u32 h1 = cvt_pk_bf16(gA1,gB1);
      float lA0 = gA0 - __uint_as_float(h0<<16);
      float lB0 = gB0 - __uint_as_float(h0 & 0xFFFF0000u);
      float lA1 = gA1 - __uint_as_float(h1<<16);
      float lB1 = gB1 - __uint_as_float(h1 & 0xFFFF0000u);
      H0[p]=h0; H1[p]=h1;
      L0[p]=cvt_pk_bf16(lA0,lB0); L1[p]=cvt_pk_bf16(lA1,lB1);
    }
    bh0[hf]=as_bf16x8(H0); bl0[hf]=as_bf16x8(L0);
    bh1[hf]=as_bf16x8(H1); bl1[hf]=as_bf16x8(L1);
  }
}

// identical 6-MFMA sequence as the old MFMA6 (same operands, same order).
#define MFMA6G(dst, A0,A1_,A2,A3, b_h0,b_h1,b_l0,b_l1)                        \
  dst = __builtin_amdgcn_mfma_f32_16x16x32_bf16(A0,  b_h0, dst, 0,0,0);       \
  dst = __builtin_amdgcn_mfma_f32_16x16x32_bf16(A1_, b_h1, dst, 0,0,0);       \
  dst = __builtin_amdgcn_mfma_f32_16x16x32_bf16(A0,  b_l0, dst, 0,0,0);       \
  dst = __builtin_amdgcn_mfma_f32_16x16x32_bf16(A1_, b_l1, dst, 0,0,0);       \
  dst = __builtin_amdgcn_mfma_f32_16x16x32_bf16(A2,  b_h0, dst, 0,0,0);       \
  dst = __builtin_amdgcn_mfma_f32_16x16x32_bf16(A3,  b_h1, dst, 0,0,0);

// load all 16 W fragments (4 channel-groups); global, L1-resident.
#define LOAD_W_ALL()                                                          \
  bf16x8 wH0[4], wH1[4], wL0[4], wL1[4];                                      \
  _Pragma("unroll")                                                           \
  for (int g=0; g<4; g++){                                                    \
    const int rA = (g*16 + col)*64 + quad*8;                                  \
    wH0[g] = *(const bf16x8*)&w2h[rA];                                        \
    wH1[g] = *(const bf16x8*)&w2h[rA+32];                                     \
    wL0[g] = *(const bf16x8*)&w2l[rA];                                        \
    wL1[g] = *(const bf16x8*)&w2l[rA+32];                                     \
  }

// Pass 2: g2 = W2@H1 + b2; per-channel sum/sumsq -> 32-way striped atomics.
// R19: zero LDS except the a1 const table.
__global__ __launch_bounds__(256) void pass2_mfma(
    const float* __restrict__ rel,
    const float* __restrict__ mom, const float* __restrict__ w1,
    const float* __restrict__ b1, const float* __restrict__ gamma,
    const float* __restrict__ beta,
    const u16* __restrict__ w2h, const u16* __restrict__ w2l,
    const float* __restrict__ b2,
    float* __restrict__ gsum32, float* __restrict__ gsq32){
  __shared__ float a1s[256];
  const int tid = threadIdx.x, blk = blockIdx.x;
  const int lane = tid & 63, wave = tid >> 6;
  const int col = lane & 15, quad = lane >> 4;
  // rel for this thread's two elements (e = (2w+t)*16+col)
  const size_t eg0 = (size_t)blk*128 + (wave*2)*16 + col;
  const float rx0 = rel[eg0*3+0], ry0 = rel[eg0*3+1], rz0 = rel[eg0*3+2];
  const float rx1 = rel[(eg0+16)*3+0], ry1 = rel[(eg0+16)*3+1], rz1 = rel[(eg0+16)*3+2];
  if (tid < 64) stats1_to_lds(tid, mom, w1, b1, gamma, beta, a1s);
  __syncthreads();
  bf16x8 bh0[2], bl0[2], bh1[2], bl1[2];
  stage2_reg(a1s, quad, rx0,ry0,rz0, rx1,ry1,rz1, bh0,bl0,bh1,bl1);
  LOAD_W_ALL()
  f32x4 acc0[4], acc1[4];
  #pragma unroll
  for (int g=0; g<4; g++){
    f32x4 a = {0.f,0.f,0.f,0.f};
    MFMA6G(a, wH0[g],wH1[g],wL0[g],wL1[g], bh0[0],bh0[1],bl0[0],bl0[1])
    acc0[g] = a;
    f32x4 b = {0.f,0.f,0.f,0.f};
    MFMA6G(b, wH0[g],wH1[g],wL0[g],wL1[g], bh1[0],bh1[1],bl1[0],bl1[1])
    acc1[g] = b;
  }
  const int st = (blk & 31)*64;
  #pragma unroll
  for (int g=0; g<4; g++){
    float4 b2v = *(const float4*)&b2[g*16 + quad*4];
    #pragma unroll
    for (int r=0; r<4; r++){
      float bb = (r==0)?b2v.x:(r==1)?b2v.y:(r==2)?b2v.z:b2v.w;
      float t0 = acc0[g][r] + bb;
      float t1 = acc1[g][r] + bb;
      float s = row_sum16(t0 + t1);
      float q = row_sum16(t0*t0 + t1*t1);
      if (col == 0){
        int ch = g*16 + quad*4 + r;
        atomicAdd(&gsum32[st+ch], s);
        atomicAdd(&gsq32[st+ch],  q);
      }
    }
  }
}

// Pass 3: H1 -> g2 -> (BN2+relu) H2 -> g3 -> max over k.
// R19: H1 in-register; H2 exchange is intra-wave via small LDS; output via
// 2KB LDS transpose to keep coalesced f32x4 stores.
__global__ __launch_bounds__(256) void pass3_mfma(
    const float* __restrict__ rel,
    const float* __restrict__ mom, const float* __restrict__ w1,
    const float* __restrict__ b1, const float* __restrict__ gamma,
    const float* __restrict__ beta,
    const u16* __restrict__ w2h, const u16* __restrict__ w2l,
    const float* __restrict__ b2,
    const float* __restrict__ gsum32, const float* __restrict__ gsq32,
    float* __restrict__ out){
  __shared__ alignas(16) u16 Hh[128*72], Hl[128*72];
  __shared__ float a1s[256];
  __shared__ float s2s[64], c2s[64];
  __shared__ float mx[512];
  const int tid = threadIdx.x, blk = blockIdx.x;
  const int lane = tid & 63, wave = tid >> 6;
  const int col = lane & 15, quad = lane >> 4;
  const size_t eg0 = (size_t)blk*128 + (wave*2)*16 + col;
  const float rx0 = rel[eg0*3+0], ry0 = rel[eg0*3+1], rz0 = rel[eg0*3+2];
  const float rx1 = rel[(eg0+16)*3+0], ry1 = rel[(eg0+16)*3+1], rz1 = rel[(eg0+16)*3+2];
  if (tid < 64){
    stats1_to_lds(tid, mom, w1, b1, gamma, beta, a1s);
  } else if (tid < 128){
    const int o = tid - 64;
    float s = 0.f, q = 0.f;
    #pragma unroll
    for (int i=0;i<32;i++){ s += gsum32[i*64+o]; q += gsq32[i*64+o]; }
    const float Minv = 1.0f / 524288.0f;
    float mu  = s*Minv;
    float var = q*Minv - mu*mu;
    float istd = rsqrtf(var + 1e-5f);
    float sc = gamma[o]*istd;
    float t2 = beta[o] - mu*sc;
    s2s[o] = sc;
    c2s[o] = fmaf(sc, b2[o], t2);
  }
  __syncthreads();
  bf16x8 bh0[2], bl0[2], bh1[2], bl1[2];
  stage2_reg(a1s, quad, rx0,ry0,rz0, rx1,ry1,rz1, bh0,bl0,bh1,bl1);
  LOAD_W_ALL()
  f32x4 acc0[4], acc1[4];
  #pragma unroll
  for (int g=0; g<4; g++){
    f32x4 a = {0.f,0.f,0.f,0.f};
    MFMA6G(a, wH0[g],wH1[g],wL0[g],wL1[g], bh0[0],bh0[1],bl0[0],bl0[1])
    acc0[g] = a;
    f32x4 b = {0.f,0.f,0.f,0.f};
    MFMA6G(b, wH0[g],wH1[g],wL0[g],wL1[g], bh1[0],bh1[1],bl1[0],bl1[1])
    acc1[g] = b;
  }
  // BN2+relu -> H2 (bf16 hi/lo), write own D-channels {g*16+quad*4..+4} of
  // own elements; consumed only by lanes of the SAME wave (intra-wave).
  float4 b2v4[4], s2v4[4], c2v4[4];
  #pragma unroll
  for (int g=0; g<4; g++){
    b2v4[g] = *(const float4*)&b2[g*16 + quad*4];
    s2v4[g] = *(const float4*)&s2s[g*16 + quad*4];
    c2v4[g] = *(const float4*)&c2s[g*16 + quad*4];
  }
  #pragma unroll
  for (int t=0; t<2; t++){
    const int e = (wave*2 + t)*16 + col;
    #pragma unroll
    for (int g=0; g<4; g++){
      f32x4 a = t ? acc1[g] : acc0[g];
      float h0 = fmaxf(fmaf(a[0]+b2v4[g].x, s2v4[g].x, c2v4[g].x), 0.0f);
      float h1 = fmaxf(fmaf(a[1]+b2v4[g].y, s2v4[g].y, c2v4[g].y), 0.0f);
      float h2 = fmaxf(fmaf(a[2]+b2v4[g].z, s2v4[g].z, c2v4[g].z), 0.0f);
      float h3 = fmaxf(fmaf(a[3]+b2v4[g].w, s2v4[g].w, c2v4[g].w), 0.0f);
      u32 h01 = cvt_pk_bf16(h0, h1);
      u32 h23 = cvt_pk_bf16(h2, h3);
      float l0 = h0 - __uint_as_float(h01 << 16);
      float l1 = h1 - __uint_as_float(h01 & 0xFFFF0000u);
      float l2 = h2 - __uint_as_float(h23 << 16);
      float l3 = h3 - __uint_as_float(h23 & 0xFFFF0000u);
      u32 l01 = cvt_pk_bf16(l0, l1);
      u32 l23 = cvt_pk_bf16(l2, l3);
      const int ch0 = g*16 + quad*4;
      *(uint2*)&Hh[e*72 + ch0] = make_uint2(h01, h23);
      *(uint2*)&Hl[e*72 + ch0] = make_uint2(l01, l23);
    }
  }
  __syncthreads();   // cheap; guarantees H2 visible (exchange is intra-wave)
  // g3 = W2@H2 for own 2 tiles; k-max over col; stage via 2KB transpose.
  #pragma unroll
  for (int t=0; t<2; t++){
    const int e = (wave*2 + t)*16 + col;
    bf16x8 ch_[2], cl_[2];
    #pragma unroll
    for (int hf=0; hf<2; hf++){
      ch_[hf] = *(const bf16x8*)&Hh[e*72 + quad*8 + hf*32];
      cl_[hf] = *(const bf16x8*)&Hl[e*72 + quad*8 + hf*32];
    }
    #pragma unroll
    for (int g=0; g<4; g++){
      f32x4 a = {0.f,0.f,0.f,0.f};
      MFMA6G(a, wH0[g],wH1[g],wL0[g],wL1[g], ch_[0],ch_[1],cl_[0],cl_[1])
      f32x4 mm;
      mm[0] = row_max16(a[0] + b2v4[g].x);
      mm[1] = row_max16(a[1] + b2v4[g].y);
      mm[2] = row_max16(a[2] + b2v4[g].z);
      mm[3] = row_max16(a[3] + b2v4[g].w);
      if (col == g)
        *(f32x4*)&mx[(wave*2 + t)*64 + g*16 + quad*4] = mm;
    }
  }
  __syncthreads();
  if (tid < 128){
    const int ch = tid >> 1, hf = tid & 1;
    f32x4 v;
    v[0] = mx[(hf*4+0)*64 + ch];
    v[1] = mx[(hf*4+1)*64 + ch];
    v[2] = mx[(hf*4+2)*64 + ch];
    v[3] = mx[(hf*4+3)*64 + ch];
    float* po = out + (((size_t)(blk>>9)*64 + ch) << 12) + (blk & 511)*8 + hf*4;
    *(f32x4*)po = v;
  }
}

extern "C" void kernel_launch(void* const* d_in, const int* in_sizes, int n_in,
                              void* d_out, int out_size, void* d_ws, size_t ws_size,
                              hipStream_t stream){
  const float* xyz   = (const float*)d_in[0];
  const float* w1    = (const float*)d_in[1];
  const float* b1    = (const float*)d_in[2];
  const float* w2    = (const float*)d_in[3];
  const float* b2    = (const float*)d_in[4];
  const float* gamma = (const float*)d_in[5];
  const float* beta  = (const float*)d_in[6];
  float* out = (float*)d_out;
  float* ws  = (float*)d_ws;

  float*  rel    = ws + REL_OFF;
  float4* pts4   = (float4*)(ws + PTS4_OFF);
  float*  mom    = ws + ACC_OFF;       // 16, zeroed in prep

  const bool big = ws_size >= (size_t)EXT_END * sizeof(float);
  u16 *w2h, *w2l; float *gsum32, *gsq32;
  if (big){
    w2h    = (u16*)(ws + EXT_OFF);
    w2l    = (u16*)(ws + EXT_OFF + 2048);
    gsum32 = ws + EXT_OFF + 4096;
    gsq32  = ws + EXT_OFF + 6144;
  } else {
    w2h    = (u16*)(ws + PTS4_OFF);
    w2l    = (u16*)(ws + PTS4_OFF + 2048);
    gsum32 = ws + PTS4_OFF + 4096;
    gsq32  = ws + PTS4_OFF + 6144;
  }

  prep_kernel  <<<128,  256, 0, stream>>>(xyz, pts4, mom, w2, w2h, w2l,
                                          gsum32, gsq32, big ? 1 : 0);
  knn_kernel   <<<1024, 256, 0, stream>>>(pts4, rel, mom);
  if (!big)
    w2prep_kernel<<<16, 256, 0, stream>>>(w2, w2h, w2l, gsum32, gsq32);
  pass2_mfma   <<<4096, 256, 0, stream>>>(rel, mom, w1, b1, gamma, beta,
                                          w2h, w2l, b2, gsum32, gsq32);
  pass3_mfma   <<<4096, 256, 0, stream>>>(rel, mom, w1, b1, gamma, beta,
                                          w2h, w2l, b2, gsum32, gsq32, out);
}

// Round 8
// 268.667 us; speedup vs baseline: 1.3162x; 1.3162x over previous
//
#include <hip/hip_runtime.h>

typedef unsigned int u32;
typedef unsigned short u16;
typedef unsigned long long u64;
typedef __attribute__((ext_vector_type(8))) short bf16x8;
typedef __attribute__((ext_vector_type(4))) float f32x4;

// ---------------- workspace layout (floats) ----------------
#define REL_OFF   0
#define PTS4_OFF  1572864   // pts4 during prep/knn (131072 fl). Fallback path
                            // reuses it (dead after knn) for w2h/w2l/gsum/gsq.
#define ACC_OFF   1703936   // mom[16]  (zeroed by prep each launch)
#define EXT_OFF   1705360   // big-ws path: w2h(2048)|w2l(2048)|gsum32(2048)|gsq32(2048)
#define EXT_END   1713552   // floats; big path needs ws_size >= EXT_END*4 bytes

// R20: exact revert to the R6 configuration (best verified: 266.4 us).
// R7's in-register pass restructure (+64 VGPR W-residency, global W loads)
// regressed +87 us -> passes are latency/occupancy-bound, NOT LDS-bound.

__device__ __forceinline__ u32 bfh(float v){           // RNE bf16 hi bits
  u32 x = __float_as_uint(v);
  return (x + 0x7FFFu + ((x >> 16) & 1u)) >> 16;
}
__device__ __forceinline__ void split2(float v, u16* hh, u16* hl){
  u32 h = bfh(v);
  float hif = __uint_as_float(h << 16);
  u32 l = bfh(v - hif);
  *hh = (u16)h; *hl = (u16)l;
}
// packed RNE bf16 convert: dst.lo = bf16(a), dst.hi = bf16(b).
__device__ __forceinline__ u32 cvt_pk_bf16(float a, float b){
  u32 r;
  asm("v_cvt_pk_bf16_f32 %0, %1, %2" : "=v"(r) : "v"(a), "v"(b));
  return r;
}

// ---- DPP rotate-reductions over the 16-lane DPP row (R18, proven) ----
template<int N>
__device__ __forceinline__ float dpp_ror_f(float x){
  int r = __builtin_amdgcn_update_dpp(__float_as_int(x), __float_as_int(x),
                                      0x120 + N, 0xf, 0xf, false);
  return __int_as_float(r);
}
__device__ __forceinline__ float row_sum16(float x){
  x += dpp_ror_f<1>(x);
  x += dpp_ror_f<2>(x);
  x += dpp_ror_f<4>(x);
  x += dpp_ror_f<8>(x);
  return x;
}
__device__ __forceinline__ float row_max16(float x){
  x = fmaxf(x, dpp_ror_f<1>(x));
  x = fmaxf(x, dpp_ror_f<2>(x));
  x = fmaxf(x, dpp_ror_f<4>(x));
  x = fmaxf(x, dpp_ror_f<8>(x));
  return x;
}

// prep absorbs W2 bf16-split + gsum/gsq zeroing (big-ws path, R17).
__global__ __launch_bounds__(256) void prep_kernel(const float* __restrict__ xyz,
                                                   float4* __restrict__ pts4,
                                                   float* __restrict__ mom,
                                                   const float* __restrict__ w2,
                                                   u16* __restrict__ w2h,
                                                   u16* __restrict__ w2l,
                                                   float* __restrict__ gsum32,
                                                   float* __restrict__ gsq32,
                                                   int do_w2){
#pragma clang fp contract(off)
  int g = blockIdx.x*256 + threadIdx.x;
  if (g < 16) mom[g] = 0.0f;
  if (do_w2){
    if (g < 4096) split2(w2[g], &w2h[g], &w2l[g]);
    if (g < 2048) gsum32[g] = 0.0f;
    else if (g < 4096) gsq32[g-2048] = 0.0f;
  }
  int b = g >> 12, n = g & 4095;
  const float* xb = xyz + (size_t)b*12288;
  float x = xb[n], y = xb[4096+n], z = xb[8192+n];
  float sq = (x*x + y*y) + z*z;
  pts4[g] = make_float4(x,y,z,sq);
}

// Fallback (small ws): W2 split + zeroing into dead pts4, after knn.
__global__ void w2prep_kernel(const float* __restrict__ w2,
                              u16* __restrict__ w2h, u16* __restrict__ w2l,
                              float* __restrict__ gsum32, float* __restrict__ gsq32){
  int i = blockIdx.x*256 + threadIdx.x;   // 4096
  split2(w2[i], &w2h[i], &w2l[i]);
  if (i < 2048) gsum32[i] = 0.0f; else gsq32[i-2048] = 0.0f;
}

// Parallel (depth-2) sorted-insert (R15).
template<int N>
__device__ __forceinline__ void chain_insert_n(double* s, double key){
  #pragma unroll
  for (int t = N-1; t >= 1; --t)
    s[t] = fmax(s[t], fmin(s[t-1], key));
  s[0] = fmax(s[0], key);
}

// KNN: burst-draining ring (R13) + parallel chain (R15). UNCHANGED.
__global__ __launch_bounds__(256) void knn_kernel(const float4* __restrict__ pts4,
                                                  float* __restrict__ rel,
                                                  float* __restrict__ mom){
#pragma clang fp contract(off)
  __shared__ double ring[4352];
  __shared__ float bmom[16];
  __shared__ u32 gate[32];
  u32* lA = (u32*)ring;
  u16* lB = (u16*)((char*)ring + 18048);
  const int tid  = threadIdx.x;
  const int lane = tid & 63;
  const int wave = tid >> 6;
  const int q    = lane & 31;
  const int h    = lane >> 5;
  const int sp   = wave*2 + h;
  const int blk  = blockIdx.x;
  const int b    = blk >> 7;
  const int q0   = (blk & 127) << 5;
  const float4* __restrict__ P = pts4 + ((size_t)b << 12);
  const float4* __restrict__ C = P + (sp << 9);
  const float4 me = P[q0 + q];
  if (tid < 16) bmom[tid] = 0.0f;
  if (tid < 32) gate[tid] = 0u;
  __syncthreads();

  double s[17];
  #pragma unroll
  for (int i=0;i<17;i++) s[i] = 0.0;
  const int base = tid*17;
  const int jg0 = sp << 9;
  u32 wr = 0, rd = 0;
  double pD_ = 0.0;
  const double kinv = 1.52587890625e-05;

  #define KEY48(u, J) ({                                              \
    float dot_ = (me.x*c[(u)].x + me.y*c[(u)].y) + me.z*c[(u)].z;     \
    float d_   = (me.w + c[(u)].w) - 2.0f*dot_;                       \
    u32 ub_ = __float_as_uint(d_);                                    \
    ub_ ^= ((u32)(((int)ub_) >> 31) | 0x80000000u);                   \
    (double)ub_ * 65536.0 + (double)(4095 - (J)); })

  { // warm-up candidates 0..7, triangular depths 1..8
    float4 c[8];
    #pragma unroll
    for (int u=0;u<8;u++) c[u] = C[u];
    chain_insert_n<1>(s, KEY48(0, jg0+0));
    chain_insert_n<2>(s, KEY48(1, jg0+1));
    chain_insert_n<3>(s, KEY48(2, jg0+2));
    chain_insert_n<4>(s, KEY48(3, jg0+3));
    chain_insert_n<5>(s, KEY48(4, jg0+4));
    chain_insert_n<6>(s, KEY48(5, jg0+5));
    chain_insert_n<7>(s, KEY48(6, jg0+6));
    chain_insert_n<8>(s, KEY48(7, jg0+7));
  }
  { // candidates 8..15, depths 9..16
    float4 c[8];
    #pragma unroll
    for (int u=0;u<8;u++) c[u] = C[8+u];
    chain_insert_n< 9>(s, KEY48(0, jg0+ 8));
    chain_insert_n<10>(s, KEY48(1, jg0+ 9));
    chain_insert_n<11>(s, KEY48(2, jg0+10));
    chain_insert_n<12>(s, KEY48(3, jg0+11));
    chain_insert_n<13>(s, KEY48(4, jg0+12));
    chain_insert_n<14>(s, KEY48(5, jg0+13));
    chain_insert_n<15>(s, KEY48(6, jg0+14));
    chain_insert_n<16>(s, KEY48(7, jg0+15));
  }
  { // candidates 16..23, full depth
    float4 c[8];
    #pragma unroll
    for (int u=0;u<8;u++) c[u] = C[16+u];
    #pragma unroll
    for (int u=0;u<8;u++) chain_insert_n<17>(s, KEY48(u, jg0+16+u));
  }

  u32 lastpub = (u32)(s[16] * kinv);
  atomicMax(&gate[q], lastpub);
  u32 ob = lastpub;

  #define INSERT_STEP() {                                        \
    bool act = rd != wr;                                         \
    double key = act ? pD_ : 0.0;                                \
    rd += act;                                                   \
    pD_ = ring[base + (int)(rd & 15u)];                          \
    if (__any(key > s[16])) chain_insert_n<17>(s, key);          \
  }

  for (int g8 = 24; g8 < 512; g8 += 8){
    if (__any((int)(wr - rd) >= 9)){
      do { INSERT_STEP(); } while (__any(rd != wr));
      ob = (u32)(s[16] * kinv);
      if (ob > lastpub){ atomicMax(&gate[q], ob); lastpub = ob; }
    }
    float4 c[8];
    #pragma unroll
    for (int u=0;u<8;u++) c[u] = C[g8 + u];
    const u32 mb = max(gate[q], ob);
    const u32 ib = (mb >> 31) ? (mb ^ 0x80000000u) : ~mb;
    const float gmin = __uint_as_float(ib);
    const u32 wr0 = wr;
    #pragma unroll
    for (int u=0;u<8;u++){
      const int j = jg0 + g8 + u;
      float dot = (me.x*c[u].x + me.y*c[u].y) + me.z*c[u].z;
      float d   = (me.w + c[u].w) - 2.0f*dot;
      if (d >= gmin){
        u32 ub = __float_as_uint(d);
        ub ^= ((u32)(((int)ub) >> 31) | 0x80000000u);
        ring[base + (int)(wr & 15u)] = (double)ub * 65536.0 + (double)(4095 - j);
        wr++;
      }
    }
    if (wr != wr0) pD_ = ring[base + (int)(rd & 15u)];
  }
  while (__any(rd != wr)) INSERT_STEP();
  #undef INSERT_STEP
  #undef KEY48

  __syncthreads();
  #pragma unroll
  for (int i=0;i<17;i++){
    const int o = (sp*17 + i)*33 + q;
    u32 hi = (u32)(s[i] * kinv);
    u32 lo = (u32)(s[i] - (double)hi * 65536.0);
    lA[o] = hi;
    lB[o] = (u16)lo;
  }
  __syncthreads();

  {
    const int mq  = tid >> 3;
    const int sub = tid & 7;
    const float4 qp = P[q0 + mq];
    float* __restrict__ ro = rel + (size_t)((b << 12) + q0 + mq) * 48;
    float sm0=0,sm1=0,sm2=0,sm3=0,sm4=0,sm5=0,sm6=0,sm7=0,sm8=0;
    int p = 0;
    for (int r=0;r<17;r++){
      const int idx = (sub*17 + p)*33 + mq;
      u64 mine = ((u64)lA[idx] << 16) | lB[idx];
      u64 kmax = mine;
      #pragma unroll
      for (int off=1; off<8; off<<=1){
        u64 o2 = __shfl_xor(kmax, off);
        kmax = (o2 > kmax) ? o2 : kmax;
      }
      p += (mine == kmax);
      if (r > 0 && sub == 0){
        const int j = 4095 - (int)(u32)(kmax & 0xFFFFull);
        const float4 nb = P[j];
        const float rx = nb.x - qp.x;
        const float ry = nb.y - qp.y;
        const float rz = nb.z - qp.z;
        ro[(r-1)*3+0] = rx; ro[(r-1)*3+1] = ry; ro[(r-1)*3+2] = rz;
        sm0 += rx; sm1 += ry; sm2 += rz;
        sm3 += rx*rx; sm4 += rx*ry; sm5 += rx*rz;
        sm6 += ry*ry; sm7 += ry*rz; sm8 += rz*rz;
      }
    }
    #pragma unroll
    for (int off=8; off<64; off<<=1){
      sm0 += __shfl_xor(sm0, off); sm1 += __shfl_xor(sm1, off); sm2 += __shfl_xor(sm2, off);
      sm3 += __shfl_xor(sm3, off); sm4 += __shfl_xor(sm4, off); sm5 += __shfl_xor(sm5, off);
      sm6 += __shfl_xor(sm6, off); sm7 += __shfl_xor(sm7, off); sm8 += __shfl_xor(sm8, off);
    }
    if (lane == 0){
      atomicAdd(&bmom[0], sm0); atomicAdd(&bmom[1], sm1); atomicAdd(&bmom[2], sm2);
      atomicAdd(&bmom[3], sm3); atomicAdd(&bmom[4], sm4); atomicAdd(&bmom[5], sm5);
      atomicAdd(&bmom[6], sm6); atomicAdd(&bmom[7], sm7); atomicAdd(&bmom[8], sm8);
    }
  }
  __syncthreads();
  if (tid < 9) atomicAdd(&mom[tid], bmom[tid]);
}

// BN1 analytic consts into LDS; __noinline__ => shared codegen in both passes.
__device__ __noinline__ void stats1_to_lds(int o, const float* __restrict__ mom,
    const float* __restrict__ w1, const float* __restrict__ b1,
    const float* __restrict__ gamma, const float* __restrict__ beta,
    float* a1){
  const float Minv = 1.0f / 524288.0f;
  float m0 = mom[0]*Minv, m1 = mom[1]*Minv, m2 = mom[2]*Minv;
  float cxx = mom[3]*Minv - m0*m0;
  float cxy = mom[4]*Minv - m0*m1;
  float cxz = mom[5]*Minv - m0*m2;
  float cyy = mom[6]*Minv - m1*m1;
  float cyz = mom[7]*Minv - m1*m2;
  float czz = mom[8]*Minv - m2*m2;
  float wx = w1[o*3+0], wy = w1[o*3+1], wz = w1[o*3+2];
  float mu  = wx*m0 + wy*m1 + wz*m2 + b1[o];
  float var = wx*wx*cxx + wy*wy*cyy + wz*wz*czz
            + 2.0f*(wx*wy*cxy + wx*wz*cxz + wy*wz*cyz);
  float istd = rsqrtf(var + 1e-5f);
  float sc = gamma[o]*istd;
  float t1 = beta[o] - mu*sc;
  a1[o*4+0] = wx*sc;
  a1[o*4+1] = wy*sc;
  a1[o*4+2] = wz*sc;
  a1[o*4+3] = fmaf(sc, b1[o], t1);
}

// ---- H1 staging core: folded layer1 + v_cvt_pk_bf16_f32 hi/lo split ----
__device__ __forceinline__ void stage_H_core(int e, int half,
    float rx, float ry, float rz, const float* a1, u16* Hh, u16* Hl){
  const float4* A1 = (const float4*)a1;
  const int ch0 = half*32;
  #pragma unroll
  for (int i=0;i<32;i+=4){
    float g[4];
    #pragma unroll
    for (int r2=0;r2<4;r2++){
      float4 a = A1[ch0+i+r2];
      float t = fmaf(a.x, rx, fmaf(a.y, ry, fmaf(a.z, rz, a.w)));
      g[r2] = fmaxf(t, 0.0f);
    }
    u32 h01 = cvt_pk_bf16(g[0], g[1]);
    u32 h23 = cvt_pk_bf16(g[2], g[3]);
    float l0 = g[0] - __uint_as_float(h01 << 16);
    float l1 = g[1] - __uint_as_float(h01 & 0xFFFF0000u);
    float l2 = g[2] - __uint_as_float(h23 << 16);
    float l3 = g[3] - __uint_as_float(h23 & 0xFFFF0000u);
    u32 l01 = cvt_pk_bf16(l0, l1);
    u32 l23 = cvt_pk_bf16(l2, l3);
    *(uint2*)&Hh[e*72 + ch0 + i] = make_uint2(h01, h23);
    *(uint2*)&Hl[e*72 + ch0 + i] = make_uint2(l01, l23);
  }
}

#define MFMA6(dst, b_h0, b_h1, b_l0, b_l1)                                   \
  dst = __builtin_amdgcn_mfma_f32_16x16x32_bf16(aH0, b_h0, dst, 0,0,0);      \
  dst = __builtin_amdgcn_mfma_f32_16x16x32_bf16(aH1, b_h1, dst, 0,0,0);      \
  dst = __builtin_amdgcn_mfma_f32_16x16x32_bf16(aH0, b_l0, dst, 0,0,0);      \
  dst = __builtin_amdgcn_mfma_f32_16x16x32_bf16(aH1, b_l1, dst, 0,0,0);      \
  dst = __builtin_amdgcn_mfma_f32_16x16x32_bf16(aL0, b_h0, dst, 0,0,0);      \
  dst = __builtin_amdgcn_mfma_f32_16x16x32_bf16(aL1, b_h1, dst, 0,0,0);

#define LOAD_W_FRAGS()                                                        \
  const int rA = (wave*16 + col)*64 + quad*8;                                 \
  bf16x8 aH0 = *(const bf16x8*)&w2h[rA];                                      \
  bf16x8 aH1 = *(const bf16x8*)&w2h[rA+32];                                   \
  bf16x8 aL0 = *(const bf16x8*)&w2l[rA];                                      \
  bf16x8 aL1 = *(const bf16x8*)&w2l[rA+32];

// Pass 2: g2 = W2@H1 + b2; per-channel sum/sumsq -> 32-way striped atomics.
__global__ __launch_bounds__(256) void pass2_mfma(
    const float* __restrict__ rel,
    const float* __restrict__ mom, const float* __restrict__ w1,
    const float* __restrict__ b1, const float* __restrict__ gamma,
    const float* __restrict__ beta,
    const u16* __restrict__ w2h, const u16* __restrict__ w2l,
    const float* __restrict__ b2,
    float* __restrict__ gsum32, float* __restrict__ gsq32){
  __shared__ alignas(16) u16 Hh[128*72], Hl[128*72];
  __shared__ float a1s[256];
  const int tid = threadIdx.x, blk = blockIdx.x;
  const int e = tid>>1, half = tid&1;
  size_t eg = (size_t)blk*128 + e;
  const float rx = rel[eg*3+0], ry = rel[eg*3+1], rz = rel[eg*3+2];
  if (tid < 64) stats1_to_lds(tid, mom, w1, b1, gamma, beta, a1s);
  __syncthreads();
  stage_H_core(e, half, rx, ry, rz, (const float*)a1s, Hh, Hl);
  __syncthreads();
  const int lane = tid & 63, wave = tid >> 6;
  const int col = lane & 15, quad = lane >> 4;
  LOAD_W_FRAGS()
  float b2v[4];
  #pragma unroll
  for (int r=0;r<4;r++) b2v[r] = b2[wave*16 + quad*4 + r];
  float ssum[4] = {0,0,0,0}, ssq[4] = {0,0,0,0};
  #pragma unroll
  for (int nt=0; nt<8; nt++){
    const int offB = (nt*16 + col)*72 + quad*8;
    bf16x8 bH0 = *(const bf16x8*)&Hh[offB];
    bf16x8 bH1 = *(const bf16x8*)&Hh[offB+32];
    bf16x8 bL0 = *(const bf16x8*)&Hl[offB];
    bf16x8 bL1 = *(const bf16x8*)&Hl[offB+32];
    f32x4 a = {0.f,0.f,0.f,0.f};
    MFMA6(a, bH0, bH1, bL0, bL1)
    #pragma unroll
    for (int r=0;r<4;r++){
      float t = a[r] + b2v[r];
      ssum[r] += t; ssq[r] += t*t;
    }
  }
  #pragma unroll
  for (int r=0;r<4;r++){
    ssum[r] = row_sum16(ssum[r]);
    ssq[r]  = row_sum16(ssq[r]);
  }
  if (col == 0){
    const int st = (blk & 31)*64;
    #pragma unroll
    for (int r=0;r<4;r++){
      int ch = wave*16 + quad*4 + r;
      atomicAdd(&gsum32[st+ch], ssum[r]);
      atomicAdd(&gsq32[st+ch],  ssq[r]);
    }
  }
}

// Pass 3: H1 -> g2 -> (BN2+relu) H2 -> g3 -> max over k.
__global__ __launch_bounds__(256) void pass3_mfma(
    const float* __restrict__ rel,
    const float* __restrict__ mom, const float* __restrict__ w1,
    const float* __restrict__ b1, const float* __restrict__ gamma,
    const float* __restrict__ beta,
    const u16* __restrict__ w2h, const u16* __restrict__ w2l,
    const float* __restrict__ b2,
    const float* __restrict__ gsum32, const float* __restrict__ gsq32,
    float* __restrict__ out){
  __shared__ alignas(16) u16 Hh[128*72], Hl[128*72];
  __shared__ float a1s[256];
  __shared__ float s2s[64], c2s[64];
  const int tid = threadIdx.x, blk = blockIdx.x;
  const int e = tid>>1, half = tid&1;
  size_t eg = (size_t)blk*128 + e;
  const float rx = rel[eg*3+0], ry = rel[eg*3+1], rz = rel[eg*3+2];
  if (tid < 64){
    stats1_to_lds(tid, mom, w1, b1, gamma, beta, a1s);
  } else if (tid < 128){
    const int o = tid - 64;
    float s = 0.f, q = 0.f;
    #pragma unroll
    for (int i=0;i<32;i++){ s += gsum32[i*64+o]; q += gsq32[i*64+o]; }
    const float Minv = 1.0f / 524288.0f;
    float mu  = s*Minv;
    float var = q*Minv - mu*mu;
    float istd = rsqrtf(var + 1e-5f);
    float sc = gamma[o]*istd;
    float t2 = beta[o] - mu*sc;
    s2s[o] = sc;
    c2s[o] = fmaf(sc, b2[o], t2);
  }
  __syncthreads();
  stage_H_core(e, half, rx, ry, rz, (const float*)a1s, Hh, Hl);
  __syncthreads();
  const int lane = tid & 63, wave = tid >> 6;
  const int col = lane & 15, quad = lane >> 4;
  LOAD_W_FRAGS()
  float s2v[4], c2v[4], b2v[4];
  #pragma unroll
  for (int r=0;r<4;r++){
    int ch = wave*16 + quad*4 + r;
    s2v[r] = s2s[ch]; c2v[r] = c2s[ch]; b2v[r] = b2[ch];
  }
  f32x4 acc[8];
  #pragma unroll
  for (int nt=0; nt<8; nt++){
    const int offB = (nt*16 + col)*72 + quad*8;
    bf16x8 bH0 = *(const bf16x8*)&Hh[offB];
    bf16x8 bH1 = *(const bf16x8*)&Hh[offB+32];
    bf16x8 bL0 = *(const bf16x8*)&Hl[offB];
    bf16x8 bL1 = *(const bf16x8*)&Hl[offB+32];
    f32x4 a = {0.f,0.f,0.f,0.f};
    MFMA6(a, bH0, bH1, bL0, bL1)
    acc[nt] = a;
  }
  __syncthreads();   // all layer-2 H reads done -> safe to overwrite with H2
  #pragma unroll
  for (int nt=0; nt<8; nt++){
    const int eo = nt*16 + col;
    const int ch0 = wave*16 + quad*4;
    float h0, h1, h2, h3;
    {
      float g0 = acc[nt][0] + b2v[0];
      float g1 = acc[nt][1] + b2v[1];
      float g2 = acc[nt][2] + b2v[2];
      float g3 = acc[nt][3] + b2v[3];
      h0 = fmaxf(fmaf(g0, s2v[0], c2v[0]), 0.0f);
      h1 = fmaxf(fmaf(g1, s2v[1], c2v[1]), 0.0f);
      h2 = fmaxf(fmaf(g2, s2v[2], c2v[2]), 0.0f);
      h3 = fmaxf(fmaf(g3, s2v[3], c2v[3]), 0.0f);
    }
    u32 h01 = cvt_pk_bf16(h0, h1);
    u32 h23 = cvt_pk_bf16(h2, h3);
    float l0 = h0 - __uint_as_float(h01 << 16);
    float l1 = h1 - __uint_as_float(h01 & 0xFFFF0000u);
    float l2 = h2 - __uint_as_float(h23 << 16);
    float l3 = h3 - __uint_as_float(h23 & 0xFFFF0000u);
    u32 l01 = cvt_pk_bf16(l0, l1);
    u32 l23 = cvt_pk_bf16(l2, l3);
    *(uint2*)&Hh[eo*72 + ch0] = make_uint2(h01, h23);
    *(uint2*)&Hl[eo*72 + ch0] = make_uint2(l01, l23);
  }
  __syncthreads();
  #pragma unroll
  for (int nt=0; nt<8; nt++){
    const int offB = (nt*16 + col)*72 + quad*8;
    bf16x8 bH0 = *(const bf16x8*)&Hh[offB];
    bf16x8 bH1 = *(const bf16x8*)&Hh[offB+32];
    bf16x8 bL0 = *(const bf16x8*)&Hl[offB];
    bf16x8 bL1 = *(const bf16x8*)&Hl[offB+32];
    f32x4 a = {0.f,0.f,0.f,0.f};
    MFMA6(a, bH0, bH1, bL0, bL1)
    acc[nt][0] = row_max16(a[0]+b2v[0]);
    acc[nt][1] = row_max16(a[1]+b2v[1]);
    acc[nt][2] = row_max16(a[2]+b2v[2]);
    acc[nt][3] = row_max16(a[3]+b2v[3]);
  }
  if (col == 0){
    const int bb = blk >> 9;
    const int n0 = (blk & 511) * 8;
    #pragma unroll
    for (int r=0;r<4;r++){
      const int ch = wave*16 + quad*4 + r;
      float* po = out + (((size_t)bb*64 + ch) << 12) + n0;
      f32x4 v0 = {acc[0][r], acc[1][r], acc[2][r], acc[3][r]};
      f32x4 v1 = {acc[4][r], acc[5][r], acc[6][r], acc[7][r]};
      *(f32x4*)po = v0;
      *((f32x4*)po + 1) = v1;
    }
  }
}

extern "C" void kernel_launch(void* const* d_in, const int* in_sizes, int n_in,
                              void* d_out, int out_size, void* d_ws, size_t ws_size,
                              hipStream_t stream){
  const float* xyz   = (const float*)d_in[0];
  const float* w1    = (const float*)d_in[1];
  const float* b1    = (const float*)d_in[2];
  const float* w2    = (const float*)d_in[3];
  const float* b2    = (const float*)d_in[4];
  const float* gamma = (const float*)d_in[5];
  const float* beta  = (const float*)d_in[6];
  float* out = (float*)d_out;
  float* ws  = (float*)d_ws;

  float*  rel    = ws + REL_OFF;
  float4* pts4   = (float4*)(ws + PTS4_OFF);
  float*  mom    = ws + ACC_OFF;       // 16, zeroed in prep

  const bool big = ws_size >= (size_t)EXT_END * sizeof(float);
  u16 *w2h, *w2l; float *gsum32, *gsq32;
  if (big){
    w2h    = (u16*)(ws + EXT_OFF);
    w2l    = (u16*)(ws + EXT_OFF + 2048);
    gsum32 = ws + EXT_OFF + 4096;
    gsq32  = ws + EXT_OFF + 6144;
  } else {
    w2h    = (u16*)(ws + PTS4_OFF);
    w2l    = (u16*)(ws + PTS4_OFF + 2048);
    gsum32 = ws + PTS4_OFF + 4096;
    gsq32  = ws + PTS4_OFF + 6144;
  }

  prep_kernel  <<<128,  256, 0, stream>>>(xyz, pts4, mom, w2, w2h, w2l,
                                          gsum32, gsq32, big ? 1 : 0);
  knn_kernel   <<<1024, 256, 0, stream>>>(pts4, rel, mom);
  if (!big)
    w2prep_kernel<<<16, 256, 0, stream>>>(w2, w2h, w2l, gsum32, gsq32);
  pass2_mfma   <<<4096, 256, 0, stream>>>(rel, mom, w1, b1, gamma, beta,
                                          w2h, w2l, b2, gsum32, gsq32);
  pass3_mfma   <<<4096, 256, 0, stream>>>(rel, mom, w1, b1, gamma, beta,
                                          w2h, w2l, b2, gsum32, gsq32, out);
}

// Round 9
// 266.300 us; speedup vs baseline: 1.3279x; 1.0089x over previous
//
#include <hip/hip_runtime.h>

typedef unsigned int u32;
typedef unsigned short u16;
typedef unsigned long long u64;
typedef __attribute__((ext_vector_type(8))) short bf16x8;
typedef __attribute__((ext_vector_type(4))) float f32x4;

// ---------------- workspace layout (floats) ----------------
#define REL_OFF   0
#define PTS4_OFF  1572864   // pts4 during prep/knn (131072 fl). Fallback path
                            // reuses it (dead after knn) for w2h/w2l/gsum/gsq.
#define ACC_OFF   1703936   // mom[16] | barrier counters (2 u32) @ +16
#define EXT_OFF   1705360   // big-ws path: w2h(2048)|w2l(2048)|gsum32(2048)|gsq32(2048)
#define EXT_END   1713552   // floats; big path needs ws_size >= EXT_END*4 bytes

__device__ __forceinline__ u32 bfh(float v){           // RNE bf16 hi bits
  u32 x = __float_as_uint(v);
  return (x + 0x7FFFu + ((x >> 16) & 1u)) >> 16;
}
__device__ __forceinline__ void split2(float v, u16* hh, u16* hl){
  u32 h = bfh(v);
  float hif = __uint_as_float(h << 16);
  u32 l = bfh(v - hif);
  *hh = (u16)h; *hl = (u16)l;
}
// packed RNE bf16 convert: dst.lo = bf16(a), dst.hi = bf16(b).
__device__ __forceinline__ u32 cvt_pk_bf16(float a, float b){
  u32 r;
  asm("v_cvt_pk_bf16_f32 %0, %1, %2" : "=v"(r) : "v"(a), "v"(b));
  return r;
}

// ---- DPP rotate-reductions over the 16-lane DPP row (R18, proven) ----
template<int N>
__device__ __forceinline__ float dpp_ror_f(float x){
  int r = __builtin_amdgcn_update_dpp(__float_as_int(x), __float_as_int(x),
                                      0x120 + N, 0xf, 0xf, false);
  return __int_as_float(r);
}
__device__ __forceinline__ float row_sum16(float x){
  x += dpp_ror_f<1>(x);
  x += dpp_ror_f<2>(x);
  x += dpp_ror_f<4>(x);
  x += dpp_ror_f<8>(x);
  return x;
}
__device__ __forceinline__ float row_max16(float x){
  x = fmaxf(x, dpp_ror_f<1>(x));
  x = fmaxf(x, dpp_ror_f<2>(x));
  x = fmaxf(x, dpp_ror_f<4>(x));
  x = fmaxf(x, dpp_ror_f<8>(x));
  return x;
}

// R21: software grid barrier for the fused pass kernel. Counter zeroed by
// prep (stream-ordered earlier). Agent-scope ordering; co-residency of all
// 1024 blocks is guaranteed by the host-side occupancy guard (>=4 blocks/CU).
__device__ __forceinline__ void grid_barrier(u32* cnt, u32 expected){
  __syncthreads();
  if (threadIdx.x == 0){
    __threadfence();   // make this block's writes (incl. atomics) visible
    atomicAdd(cnt, 1u);
    while (__hip_atomic_load(cnt, __ATOMIC_ACQUIRE, __HIP_MEMORY_SCOPE_AGENT)
           < expected)
      __builtin_amdgcn_s_sleep(2);
    __threadfence();
  }
  __syncthreads();
}

// prep absorbs W2 bf16-split + gsum/gsq zeroing (big-ws path, R17) and now
// also zeroes the grid-barrier counters (R21).
__global__ __launch_bounds__(256) void prep_kernel(const float* __restrict__ xyz,
                                                   float4* __restrict__ pts4,
                                                   float* __restrict__ mom,
                                                   const float* __restrict__ w2,
                                                   u16* __restrict__ w2h,
                                                   u16* __restrict__ w2l,
                                                   float* __restrict__ gsum32,
                                                   float* __restrict__ gsq32,
                                                   u32* __restrict__ cnt,
                                                   int do_w2){
#pragma clang fp contract(off)
  int g = blockIdx.x*256 + threadIdx.x;
  if (g < 16) mom[g] = 0.0f;
  if (g >= 16 && g < 18) cnt[g-16] = 0u;
  if (do_w2){
    if (g < 4096) split2(w2[g], &w2h[g], &w2l[g]);
    if (g < 2048) gsum32[g] = 0.0f;
    else if (g < 4096) gsq32[g-2048] = 0.0f;
  }
  int b = g >> 12, n = g & 4095;
  const float* xb = xyz + (size_t)b*12288;
  float x = xb[n], y = xb[4096+n], z = xb[8192+n];
  float sq = (x*x + y*y) + z*z;
  pts4[g] = make_float4(x,y,z,sq);
}

// Fallback (small ws): W2 split + zeroing into dead pts4, after knn.
__global__ void w2prep_kernel(const float* __restrict__ w2,
                              u16* __restrict__ w2h, u16* __restrict__ w2l,
                              float* __restrict__ gsum32, float* __restrict__ gsq32){
  int i = blockIdx.x*256 + threadIdx.x;   // 4096
  split2(w2[i], &w2h[i], &w2l[i]);
  if (i < 2048) gsum32[i] = 0.0f; else gsq32[i-2048] = 0.0f;
}

// Parallel (depth-2) sorted-insert (R15).
template<int N>
__device__ __forceinline__ void chain_insert_n(double* s, double key){
  #pragma unroll
  for (int t = N-1; t >= 1; --t)
    s[t] = fmax(s[t], fmin(s[t-1], key));
  s[0] = fmax(s[0], key);
}

// KNN: burst-draining ring (R13) + parallel chain (R15). UNCHANGED.
__global__ __launch_bounds__(256) void knn_kernel(const float4* __restrict__ pts4,
                                                  float* __restrict__ rel,
                                                  float* __restrict__ mom){
#pragma clang fp contract(off)
  __shared__ double ring[4352];
  __shared__ float bmom[16];
  __shared__ u32 gate[32];
  u32* lA = (u32*)ring;
  u16* lB = (u16*)((char*)ring + 18048);
  const int tid  = threadIdx.x;
  const int lane = tid & 63;
  const int wave = tid >> 6;
  const int q    = lane & 31;
  const int h    = lane >> 5;
  const int sp   = wave*2 + h;
  const int blk  = blockIdx.x;
  const int b    = blk >> 7;
  const int q0   = (blk & 127) << 5;
  const float4* __restrict__ P = pts4 + ((size_t)b << 12);
  const float4* __restrict__ C = P + (sp << 9);
  const float4 me = P[q0 + q];
  if (tid < 16) bmom[tid] = 0.0f;
  if (tid < 32) gate[tid] = 0u;
  __syncthreads();

  double s[17];
  #pragma unroll
  for (int i=0;i<17;i++) s[i] = 0.0;
  const int base = tid*17;
  const int jg0 = sp << 9;
  u32 wr = 0, rd = 0;
  double pD_ = 0.0;
  const double kinv = 1.52587890625e-05;

  #define KEY48(u, J) ({                                              \
    float dot_ = (me.x*c[(u)].x + me.y*c[(u)].y) + me.z*c[(u)].z;     \
    float d_   = (me.w + c[(u)].w) - 2.0f*dot_;                       \
    u32 ub_ = __float_as_uint(d_);                                    \
    ub_ ^= ((u32)(((int)ub_) >> 31) | 0x80000000u);                   \
    (double)ub_ * 65536.0 + (double)(4095 - (J)); })

  { // warm-up candidates 0..7, triangular depths 1..8
    float4 c[8];
    #pragma unroll
    for (int u=0;u<8;u++) c[u] = C[u];
    chain_insert_n<1>(s, KEY48(0, jg0+0));
    chain_insert_n<2>(s, KEY48(1, jg0+1));
    chain_insert_n<3>(s, KEY48(2, jg0+2));
    chain_insert_n<4>(s, KEY48(3, jg0+3));
    chain_insert_n<5>(s, KEY48(4, jg0+4));
    chain_insert_n<6>(s, KEY48(5, jg0+5));
    chain_insert_n<7>(s, KEY48(6, jg0+6));
    chain_insert_n<8>(s, KEY48(7, jg0+7));
  }
  { // candidates 8..15, depths 9..16
    float4 c[8];
    #pragma unroll
    for (int u=0;u<8;u++) c[u] = C[8+u];
    chain_insert_n< 9>(s, KEY48(0, jg0+ 8));
    chain_insert_n<10>(s, KEY48(1, jg0+ 9));
    chain_insert_n<11>(s, KEY48(2, jg0+10));
    chain_insert_n<12>(s, KEY48(3, jg0+11));
    chain_insert_n<13>(s, KEY48(4, jg0+12));
    chain_insert_n<14>(s, KEY48(5, jg0+13));
    chain_insert_n<15>(s, KEY48(6, jg0+14));
    chain_insert_n<16>(s, KEY48(7, jg0+15));
  }
  { // candidates 16..23, full depth
    float4 c[8];
    #pragma unroll
    for (int u=0;u<8;u++) c[u] = C[16+u];
    #pragma unroll
    for (int u=0;u<8;u++) chain_insert_n<17>(s, KEY48(u, jg0+16+u));
  }

  u32 lastpub = (u32)(s[16] * kinv);
  atomicMax(&gate[q], lastpub);
  u32 ob = lastpub;

  #define INSERT_STEP() {                                        \
    bool act = rd != wr;                                         \
    double key = act ? pD_ : 0.0;                                \
    rd += act;                                                   \
    pD_ = ring[base + (int)(rd & 15u)];                          \
    if (__any(key > s[16])) chain_insert_n<17>(s, key);          \
  }

  for (int g8 = 24; g8 < 512; g8 += 8){
    if (__any((int)(wr - rd) >= 9)){
      do { INSERT_STEP(); } while (__any(rd != wr));
      ob = (u32)(s[16] * kinv);
      if (ob > lastpub){ atomicMax(&gate[q], ob); lastpub = ob; }
    }
    float4 c[8];
    #pragma unroll
    for (int u=0;u<8;u++) c[u] = C[g8 + u];
    const u32 mb = max(gate[q], ob);
    const u32 ib = (mb >> 31) ? (mb ^ 0x80000000u) : ~mb;
    const float gmin = __uint_as_float(ib);
    const u32 wr0 = wr;
    #pragma unroll
    for (int u=0;u<8;u++){
      const int j = jg0 + g8 + u;
      float dot = (me.x*c[u].x + me.y*c[u].y) + me.z*c[u].z;
      float d   = (me.w + c[u].w) - 2.0f*dot;
      if (d >= gmin){
        u32 ub = __float_as_uint(d);
        ub ^= ((u32)(((int)ub) >> 31) | 0x80000000u);
        ring[base + (int)(wr & 15u)] = (double)ub * 65536.0 + (double)(4095 - j);
        wr++;
      }
    }
    if (wr != wr0) pD_ = ring[base + (int)(rd & 15u)];
  }
  while (__any(rd != wr)) INSERT_STEP();
  #undef INSERT_STEP
  #undef KEY48

  __syncthreads();
  #pragma unroll
  for (int i=0;i<17;i++){
    const int o = (sp*17 + i)*33 + q;
    u32 hi = (u32)(s[i] * kinv);
    u32 lo = (u32)(s[i] - (double)hi * 65536.0);
    lA[o] = hi;
    lB[o] = (u16)lo;
  }
  __syncthreads();

  {
    const int mq  = tid >> 3;
    const int sub = tid & 7;
    const float4 qp = P[q0 + mq];
    float* __restrict__ ro = rel + (size_t)((b << 12) + q0 + mq) * 48;
    float sm0=0,sm1=0,sm2=0,sm3=0,sm4=0,sm5=0,sm6=0,sm7=0,sm8=0;
    int p = 0;
    for (int r=0;r<17;r++){
      const int idx = (sub*17 + p)*33 + mq;
      u64 mine = ((u64)lA[idx] << 16) | lB[idx];
      u64 kmax = mine;
      #pragma unroll
      for (int off=1; off<8; off<<=1){
        u64 o2 = __shfl_xor(kmax, off);
        kmax = (o2 > kmax) ? o2 : kmax;
      }
      p += (mine == kmax);
      if (r > 0 && sub == 0){
        const int j = 4095 - (int)(u32)(kmax & 0xFFFFull);
        const float4 nb = P[j];
        const float rx = nb.x - qp.x;
        const float ry = nb.y - qp.y;
        const float rz = nb.z - qp.z;
        ro[(r-1)*3+0] = rx; ro[(r-1)*3+1] = ry; ro[(r-1)*3+2] = rz;
        sm0 += rx; sm1 += ry; sm2 += rz;
        sm3 += rx*rx; sm4 += rx*ry; sm5 += rx*rz;
        sm6 += ry*ry; sm7 += ry*rz; sm8 += rz*rz;
      }
    }
    #pragma unroll
    for (int off=8; off<64; off<<=1){
      sm0 += __shfl_xor(sm0, off); sm1 += __shfl_xor(sm1, off); sm2 += __shfl_xor(sm2, off);
      sm3 += __shfl_xor(sm3, off); sm4 += __shfl_xor(sm4, off); sm5 += __shfl_xor(sm5, off);
      sm6 += __shfl_xor(sm6, off); sm7 += __shfl_xor(sm7, off); sm8 += __shfl_xor(sm8, off);
    }
    if (lane == 0){
      atomicAdd(&bmom[0], sm0); atomicAdd(&bmom[1], sm1); atomicAdd(&bmom[2], sm2);
      atomicAdd(&bmom[3], sm3); atomicAdd(&bmom[4], sm4); atomicAdd(&bmom[5], sm5);
      atomicAdd(&bmom[6], sm6); atomicAdd(&bmom[7], sm7); atomicAdd(&bmom[8], sm8);
    }
  }
  __syncthreads();
  if (tid < 9) atomicAdd(&mom[tid], bmom[tid]);
}

// BN1 analytic consts into LDS; __noinline__ => shared codegen everywhere.
__device__ __noinline__ void stats1_to_lds(int o, const float* __restrict__ mom,
    const float* __restrict__ w1, const float* __restrict__ b1,
    const float* __restrict__ gamma, const float* __restrict__ beta,
    float* a1){
  const float Minv = 1.0f / 524288.0f;
  float m0 = mom[0]*Minv, m1 = mom[1]*Minv, m2 = mom[2]*Minv;
  float cxx = mom[3]*Minv - m0*m0;
  float cxy = mom[4]*Minv - m0*m1;
  float cxz = mom[5]*Minv - m0*m2;
  float cyy = mom[6]*Minv - m1*m1;
  float cyz = mom[7]*Minv - m1*m2;
  float czz = mom[8]*Minv - m2*m2;
  float wx = w1[o*3+0], wy = w1[o*3+1], wz = w1[o*3+2];
  float mu  = wx*m0 + wy*m1 + wz*m2 + b1[o];
  float var = wx*wx*cxx + wy*wy*cyy + wz*wz*czz
            + 2.0f*(wx*wy*cxy + wx*wz*cxz + wy*wz*cyz);
  float istd = rsqrtf(var + 1e-5f);
  float sc = gamma[o]*istd;
  float t1 = beta[o] - mu*sc;
  a1[o*4+0] = wx*sc;
  a1[o*4+1] = wy*sc;
  a1[o*4+2] = wz*sc;
  a1[o*4+3] = fmaf(sc, b1[o], t1);
}

// BN2 consts from the 32-way striped sums (exact stats2 summation order).
__device__ __forceinline__ void stats2_to_lds(int o,
    const float* __restrict__ gsum32, const float* __restrict__ gsq32,
    const float* __restrict__ b2, const float* __restrict__ gamma,
    const float* __restrict__ beta, float* s2s, float* c2s){
  float s = 0.f, q = 0.f;
  #pragma unroll
  for (int i=0;i<32;i++){ s += gsum32[i*64+o]; q += gsq32[i*64+o]; }
  const float Minv = 1.0f / 524288.0f;
  float mu  = s*Minv;
  float var = q*Minv - mu*mu;
  float istd = rsqrtf(var + 1e-5f);
  float sc = gamma[o]*istd;
  float t2 = beta[o] - mu*sc;
  s2s[o] = sc;
  c2s[o] = fmaf(sc, b2[o], t2);
}

// ---- H1 staging core: folded layer1 + v_cvt_pk_bf16_f32 hi/lo split ----
__device__ __forceinline__ void stage_H_core(int e, int half,
    float rx, float ry, float rz, const float* a1, u16* Hh, u16* Hl){
  const float4* A1 = (const float4*)a1;
  const int ch0 = half*32;
  #pragma unroll
  for (int i=0;i<32;i+=4){
    float g[4];
    #pragma unroll
    for (int r2=0;r2<4;r2++){
      float4 a = A1[ch0+i+r2];
      float t = fmaf(a.x, rx, fmaf(a.y, ry, fmaf(a.z, rz, a.w)));
      g[r2] = fmaxf(t, 0.0f);
    }
    u32 h01 = cvt_pk_bf16(g[0], g[1]);
    u32 h23 = cvt_pk_bf16(g[2], g[3]);
    float l0 = g[0] - __uint_as_float(h01 << 16);
    float l1 = g[1] - __uint_as_float(h01 & 0xFFFF0000u);
    float l2 = g[2] - __uint_as_float(h23 << 16);
    float l3 = g[3] - __uint_as_float(h23 & 0xFFFF0000u);
    u32 l01 = cvt_pk_bf16(l0, l1);
    u32 l23 = cvt_pk_bf16(l2, l3);
    *(uint2*)&Hh[e*72 + ch0 + i] = make_uint2(h01, h23);
    *(uint2*)&Hl[e*72 + ch0 + i] = make_uint2(l01, l23);
  }
}

#define MFMA6(dst, b_h0, b_h1, b_l0, b_l1)                                   \
  dst = __builtin_amdgcn_mfma_f32_16x16x32_bf16(aH0, b_h0, dst, 0,0,0);      \
  dst = __builtin_amdgcn_mfma_f32_16x16x32_bf16(aH1, b_h1, dst, 0,0,0);      \
  dst = __builtin_amdgcn_mfma_f32_16x16x32_bf16(aH0, b_l0, dst, 0,0,0);      \
  dst = __builtin_amdgcn_mfma_f32_16x16x32_bf16(aH1, b_l1, dst, 0,0,0);      \
  dst = __builtin_amdgcn_mfma_f32_16x16x32_bf16(aL0, b_h0, dst, 0,0,0);      \
  dst = __builtin_amdgcn_mfma_f32_16x16x32_bf16(aL1, b_h1, dst, 0,0,0);

#define LOAD_W_FRAGS()                                                        \
  const int rA = (wave*16 + col)*64 + quad*8;                                 \
  bf16x8 aH0 = *(const bf16x8*)&w2h[rA];                                      \
  bf16x8 aH1 = *(const bf16x8*)&w2h[rA+32];                                   \
  bf16x8 aL0 = *(const bf16x8*)&w2l[rA];                                      \
  bf16x8 aL1 = *(const bf16x8*)&w2l[rA+32];

// ---- Pass-2 tile body (verbatim R6 logic). Trailing sync protects re-stage.
__device__ __forceinline__ void pass2_tile(int blk, int tid,
    const float* __restrict__ rel, const float* a1s,
    const u16* __restrict__ w2h, const u16* __restrict__ w2l,
    const float* __restrict__ b2,
    float* __restrict__ gsum32, float* __restrict__ gsq32,
    u16* Hh, u16* Hl){
  const int e = tid>>1, half = tid&1;
  size_t eg = (size_t)blk*128 + e;
  const float rx = rel[eg*3+0], ry = rel[eg*3+1], rz = rel[eg*3+2];
  stage_H_core(e, half, rx, ry, rz, a1s, Hh, Hl);
  __syncthreads();
  const int lane = tid & 63, wave = tid >> 6;
  const int col = lane & 15, quad = lane >> 4;
  LOAD_W_FRAGS()
  float b2v[4];
  #pragma unroll
  for (int r=0;r<4;r++) b2v[r] = b2[wave*16 + quad*4 + r];
  float ssum[4] = {0,0,0,0}, ssq[4] = {0,0,0,0};
  #pragma unroll
  for (int nt=0; nt<8; nt++){
    const int offB = (nt*16 + col)*72 + quad*8;
    bf16x8 bH0 = *(const bf16x8*)&Hh[offB];
    bf16x8 bH1 = *(const bf16x8*)&Hh[offB+32];
    bf16x8 bL0 = *(const bf16x8*)&Hl[offB];
    bf16x8 bL1 = *(const bf16x8*)&Hl[offB+32];
    f32x4 a = {0.f,0.f,0.f,0.f};
    MFMA6(a, bH0, bH1, bL0, bL1)
    #pragma unroll
    for (int r=0;r<4;r++){
      float t = a[r] + b2v[r];
      ssum[r] += t; ssq[r] += t*t;
    }
  }
  #pragma unroll
  for (int r=0;r<4;r++){
    ssum[r] = row_sum16(ssum[r]);
    ssq[r]  = row_sum16(ssq[r]);
  }
  if (col == 0){
    const int st = (blk & 31)*64;
    #pragma unroll
    for (int r=0;r<4;r++){
      int ch = wave*16 + quad*4 + r;
      atomicAdd(&gsum32[st+ch], ssum[r]);
      atomicAdd(&gsq32[st+ch],  ssq[r]);
    }
  }
  __syncthreads();
}

// ---- Pass-3 tile body (verbatim R6 logic). Trailing sync protects re-stage.
__device__ __forceinline__ void pass3_tile(int blk, int tid,
    const float* __restrict__ rel, const float* a1s,
    const float* s2s, const float* c2s,
    const u16* __restrict__ w2h, const u16* __restrict__ w2l,
    const float* __restrict__ b2, float* __restrict__ out,
    u16* Hh, u16* Hl){
  const int e = tid>>1, half = tid&1;
  size_t eg = (size_t)blk*128 + e;
  const float rx = rel[eg*3+0], ry = rel[eg*3+1], rz = rel[eg*3+2];
  stage_H_core(e, half, rx, ry, rz, a1s, Hh, Hl);
  __syncthreads();
  const int lane = tid & 63, wave = tid >> 6;
  const int col = lane & 15, quad = lane >> 4;
  LOAD_W_FRAGS()
  float s2v[4], c2v[4], b2v[4];
  #pragma unroll
  for (int r=0;r<4;r++){
    int ch = wave*16 + quad*4 + r;
    s2v[r] = s2s[ch]; c2v[r] = c2s[ch]; b2v[r] = b2[ch];
  }
  f32x4 acc[8];
  #pragma unroll
  for (int nt=0; nt<8; nt++){
    const int offB = (nt*16 + col)*72 + quad*8;
    bf16x8 bH0 = *(const bf16x8*)&Hh[offB];
    bf16x8 bH1 = *(const bf16x8*)&Hh[offB+32];
    bf16x8 bL0 = *(const bf16x8*)&Hl[offB];
    bf16x8 bL1 = *(const bf16x8*)&Hl[offB+32];
    f32x4 a = {0.f,0.f,0.f,0.f};
    MFMA6(a, bH0, bH1, bL0, bL1)
    acc[nt] = a;
  }
  __syncthreads();   // all layer-2 H reads done -> safe to overwrite with H2
  #pragma unroll
  for (int nt=0; nt<8; nt++){
    const int eo = nt*16 + col;
    const int ch0 = wave*16 + quad*4;
    float h0, h1, h2, h3;
    {
      float g0 = acc[nt][0] + b2v[0];
      float g1 = acc[nt][1] + b2v[1];
      float g2 = acc[nt][2] + b2v[2];
      float g3 = acc[nt][3] + b2v[3];
      h0 = fmaxf(fmaf(g0, s2v[0], c2v[0]), 0.0f);
      h1 = fmaxf(fmaf(g1, s2v[1], c2v[1]), 0.0f);
      h2 = fmaxf(fmaf(g2, s2v[2], c2v[2]), 0.0f);
      h3 = fmaxf(fmaf(g3, s2v[3], c2v[3]), 0.0f);
    }
    u32 h01 = cvt_pk_bf16(h0, h1);
    u32 h23 = cvt_pk_bf16(h2, h3);
    float l0 = h0 - __uint_as_float(h01 << 16);
    float l1 = h1 - __uint_as_float(h01 & 0xFFFF0000u);
    float l2 = h2 - __uint_as_float(h23 << 16);
    float l3 = h3 - __uint_as_float(h23 & 0xFFFF0000u);
    u32 l01 = cvt_pk_bf16(l0, l1);
    u32 l23 = cvt_pk_bf16(l2, l3);
    *(uint2*)&Hh[eo*72 + ch0] = make_uint2(h01, h23);
    *(uint2*)&Hl[eo*72 + ch0] = make_uint2(l01, l23);
  }
  __syncthreads();
  #pragma unroll
  for (int nt=0; nt<8; nt++){
    const int offB = (nt*16 + col)*72 + quad*8;
    bf16x8 bH0 = *(const bf16x8*)&Hh[offB];
    bf16x8 bH1 = *(const bf16x8*)&Hh[offB+32];
    bf16x8 bL0 = *(const bf16x8*)&Hl[offB];
    bf16x8 bL1 = *(const bf16x8*)&Hl[offB+32];
    f32x4 a = {0.f,0.f,0.f,0.f};
    MFMA6(a, bH0, bH1, bL0, bL1)
    acc[nt][0] = row_max16(a[0]+b2v[0]);
    acc[nt][1] = row_max16(a[1]+b2v[1]);
    acc[nt][2] = row_max16(a[2]+b2v[2]);
    acc[nt][3] = row_max16(a[3]+b2v[3]);
  }
  if (col == 0){
    const int bb = blk >> 9;
    const int n0 = (blk & 511) * 8;
    #pragma unroll
    for (int r=0;r<4;r++){
      const int ch = wave*16 + quad*4 + r;
      float* po = out + (((size_t)bb*64 + ch) << 12) + n0;
      f32x4 v0 = {acc[0][r], acc[1][r], acc[2][r], acc[3][r]};
      f32x4 v1 = {acc[4][r], acc[5][r], acc[6][r], acc[7][r]};
      *(f32x4*)po = v0;
      *((f32x4*)po + 1) = v1;
    }
  }
  __syncthreads();
}

// Fallback kernels (proven R6 path), thin wrappers over the tile bodies.
__global__ __launch_bounds__(256) void pass2_mfma(
    const float* __restrict__ rel,
    const float* __restrict__ mom, const float* __restrict__ w1,
    const float* __restrict__ b1, const float* __restrict__ gamma,
    const float* __restrict__ beta,
    const u16* __restrict__ w2h, const u16* __restrict__ w2l,
    const float* __restrict__ b2,
    float* __restrict__ gsum32, float* __restrict__ gsq32){
  __shared__ alignas(16) u16 Hh[128*72], Hl[128*72];
  __shared__ float a1s[256];
  const int tid = threadIdx.x;
  if (tid < 64) stats1_to_lds(tid, mom, w1, b1, gamma, beta, a1s);
  __syncthreads();
  pass2_tile(blockIdx.x, tid, rel, a1s, w2h, w2l, b2, gsum32, gsq32, Hh, Hl);
}

__global__ __launch_bounds__(256) void pass3_mfma(
    const float* __restrict__ rel,
    const float* __restrict__ mom, const float* __restrict__ w1,
    const float* __restrict__ b1, const float* __restrict__ gamma,
    const float* __restrict__ beta,
    const u16* __restrict__ w2h, const u16* __restrict__ w2l,
    const float* __restrict__ b2,
    const float* __restrict__ gsum32, const float* __restrict__ gsq32,
    float* __restrict__ out){
  __shared__ alignas(16) u16 Hh[128*72], Hl[128*72];
  __shared__ float a1s[256];
  __shared__ float s2s[64], c2s[64];
  const int tid = threadIdx.x;
  if (tid < 64) stats1_to_lds(tid, mom, w1, b1, gamma, beta, a1s);
  else if (tid < 128) stats2_to_lds(tid-64, gsum32, gsq32, b2, gamma, beta, s2s, c2s);
  __syncthreads();
  pass3_tile(blockIdx.x, tid, rel, a1s, s2s, c2s, w2h, w2l, b2, out, Hh, Hl);
}

// R21: fused persistent pass kernel. 1024 blocks x (4 pass2 tiles -> grid
// barrier -> BN2 consts -> 4 pass3 tiles). Launched only when the occupancy
// guard confirms >=4 blocks/CU (all 1024 co-resident).
__global__ __launch_bounds__(256) void fused_pass(
    const float* __restrict__ rel,
    const float* __restrict__ mom, const float* __restrict__ w1,
    const float* __restrict__ b1, const float* __restrict__ gamma,
    const float* __restrict__ beta,
    const u16* __restrict__ w2h, const u16* __restrict__ w2l,
    const float* __restrict__ b2,
    float* __restrict__ gsum32, float* __restrict__ gsq32,
    float* __restrict__ out, u32* __restrict__ cnt){
  __shared__ alignas(16) u16 Hh[128*72], Hl[128*72];
  __shared__ float a1s[256];
  __shared__ float s2s[64], c2s[64];
  const int tid = threadIdx.x, bid = blockIdx.x;
  if (tid < 64) stats1_to_lds(tid, mom, w1, b1, gamma, beta, a1s);
  __syncthreads();
  #pragma unroll 1
  for (int t=0; t<4; t++)
    pass2_tile(t*1024 + bid, tid, rel, a1s, w2h, w2l, b2, gsum32, gsq32, Hh, Hl);
  grid_barrier(cnt, 1024u);
  if (tid >= 64 && tid < 128)
    stats2_to_lds(tid-64, gsum32, gsq32, b2, gamma, beta, s2s, c2s);
  __syncthreads();
  #pragma unroll 1
  for (int t=0; t<4; t++)
    pass3_tile(t*1024 + bid, tid, rel, a1s, s2s, c2s, w2h, w2l, b2, out, Hh, Hl);
}

extern "C" void kernel_launch(void* const* d_in, const int* in_sizes, int n_in,
                              void* d_out, int out_size, void* d_ws, size_t ws_size,
                              hipStream_t stream){
  const float* xyz   = (const float*)d_in[0];
  const float* w1    = (const float*)d_in[1];
  const float* b1    = (const float*)d_in[2];
  const float* w2    = (const float*)d_in[3];
  const float* b2    = (const float*)d_in[4];
  const float* gamma = (const float*)d_in[5];
  const float* beta  = (const float*)d_in[6];
  float* out = (float*)d_out;
  float* ws  = (float*)d_ws;

  float*  rel    = ws + REL_OFF;
  float4* pts4   = (float4*)(ws + PTS4_OFF);
  float*  mom    = ws + ACC_OFF;                 // 16, zeroed in prep
  u32*    cnt    = (u32*)(ws + ACC_OFF + 16);    // 2 u32, zeroed in prep

  const bool big = ws_size >= (size_t)EXT_END * sizeof(float);
  u16 *w2h, *w2l; float *gsum32, *gsq32;
  if (big){
    w2h    = (u16*)(ws + EXT_OFF);
    w2l    = (u16*)(ws + EXT_OFF + 2048);
    gsum32 = ws + EXT_OFF + 4096;
    gsq32  = ws + EXT_OFF + 6144;
  } else {
    w2h    = (u16*)(ws + PTS4_OFF);
    w2l    = (u16*)(ws + PTS4_OFF + 2048);
    gsum32 = ws + PTS4_OFF + 4096;
    gsq32  = ws + PTS4_OFF + 6144;
  }

  // Occupancy guard for the fused path: all 1024 blocks must be co-resident.
  int nb = 0;
  hipError_t oe = hipOccupancyMaxActiveBlocksPerMultiprocessor(&nb, fused_pass, 256, 0);
  const bool fuse = (oe == hipSuccess) && (nb >= 4);

  prep_kernel  <<<128,  256, 0, stream>>>(xyz, pts4, mom, w2, w2h, w2l,
                                          gsum32, gsq32, cnt, big ? 1 : 0);
  knn_kernel   <<<1024, 256, 0, stream>>>(pts4, rel, mom);
  if (!big)
    w2prep_kernel<<<16, 256, 0, stream>>>(w2, w2h, w2l, gsum32, gsq32);

  if (fuse){
    fused_pass <<<1024, 256, 0, stream>>>(rel, mom, w1, b1, gamma, beta,
                                          w2h, w2l, b2, gsum32, gsq32, out, cnt);
  } else {
    pass2_mfma <<<4096, 256, 0, stream>>>(rel, mom, w1, b1, gamma, beta,
                                          w2h, w2l, b2, gsum32, gsq32);
    pass3_mfma <<<4096, 256, 0, stream>>>(rel, mom, w1, b1, gamma, beta,
                                          w2h, w2l, b2, gsum32, gsq32, out);
  }
}